// Round 9
// baseline (464.458 us; speedup 1.0000x reference)
//
#include <hip/hip_runtime.h>
#include <hip/hip_bf16.h>

typedef __bf16 bf16;
typedef __bf16 bf16x8 __attribute__((ext_vector_type(8)));
typedef __bf16 bf16x4 __attribute__((ext_vector_type(4)));
typedef float f32x4 __attribute__((ext_vector_type(4)));
typedef unsigned int u32;
typedef unsigned short u16;

constexpr int B_ = 4, S = 2048, D = 1024, H = 16, HD = 64;
constexpr int M = B_ * S;  // 8192

#define MFMA(a, b, c) __builtin_amdgcn_mfma_f32_16x16x32_bf16(a, b, c, 0, 0, 0)

// ---- async global->LDS, 16 B per lane (dest = wave-uniform base + lane*16) ----
__device__ inline void gl_lds16(const bf16* g, bf16* l) {
  __builtin_amdgcn_global_load_lds(
      (const __attribute__((address_space(1))) u32*)g,
      (__attribute__((address_space(3))) u32*)l, 16, 0, 0);
}

__device__ inline bf16x8 load8(const void* base, size_t idx, bool isf32) {
  if (isf32) {
    const float* p = (const float*)base + idx;
    const float4 a = *(const float4*)p;
    const float4 b = *(const float4*)(p + 4);
    bf16x8 r;
    r[0] = (bf16)a.x; r[1] = (bf16)a.y; r[2] = (bf16)a.z; r[3] = (bf16)a.w;
    r[4] = (bf16)b.x; r[5] = (bf16)b.y; r[6] = (bf16)b.z; r[7] = (bf16)b.w;
    return r;
  }
  return *(const bf16x8*)((const bf16*)base + idx);
}
__device__ inline float load1(const void* base, size_t idx, bool isf32) {
  return isf32 ? ((const float*)base)[idx] : (float)((const bf16*)base)[idx];
}
// 4 consecutive values (idx multiple of 4 -> aligned)
__device__ inline f32x4 load4(const void* base, size_t idx, bool isf32) {
  if (isf32) {
    const float4 v = *(const float4*)((const float*)base + idx);
    return {v.x, v.y, v.z, v.w};
  }
  const bf16x4 v = *(const bf16x4*)((const bf16*)base + idx);
  return {(float)v[0], (float)v[1], (float)v[2], (float)v[3]};
}

// ---------------------------------------------------------------------------
__global__ __launch_bounds__(256) void detect_dtype(const uint4* __restrict__ X,
                                                    int* __restrict__ flag) {
  bool hit = false;
  for (int i = threadIdx.x; i < 32768; i += 256) {
    const uint4 v = X[i];
    const u32 w[4] = {v.x, v.y, v.z, v.w};
#pragma unroll
    for (int j = 0; j < 4; j++) {
      if (((w[j] >> 7) & 0xFFu) == 0xFFu) hit = true;
      if (((w[j] >> 23) & 0xFFu) == 0xFFu) hit = true;
    }
  }
  __shared__ int s;
  if (threadIdx.x == 0) s = 0;
  __syncthreads();
  if (hit) atomicOr(&s, 1);
  __syncthreads();
  if (threadIdx.x == 0) *flag = s;
}

// ---------------------------------------------------------------------------
// fp32 only: convert X -> Xb (d_out[0,16MB)), W q/k/v -> Wb (d_out+16MB).
// ---------------------------------------------------------------------------
__global__ __launch_bounds__(256) void convert_inputs(
    const void* __restrict__ X, const void* __restrict__ W0,
    const void* __restrict__ W1, const void* __restrict__ W2,
    bf16* __restrict__ Xb, bf16* __restrict__ Wb,
    const int* __restrict__ flagp) {
  if (*flagp == 0) return;
  const int seg = blockIdx.y;
  const size_t n = (seg == 0) ? (size_t)M * D : (size_t)D * D;
  const size_t i0 = ((size_t)blockIdx.x * 256 + threadIdx.x) * 8;
  if (i0 >= n) return;
  const void* src = seg == 0 ? X : seg == 1 ? W0 : seg == 2 ? W1 : W2;
  bf16* dst = seg == 0 ? Xb : Wb + (size_t)(seg - 1) * D * D;
  *(bf16x8*)(dst + i0) = load8(src, i0, true);
}

// ---------------------------------------------------------------------------
// QKV GEMM, grid.z = {Q,K,V}. Async-staged bf16 A and B (m97 path).
// z==0: Q*(0.125*log2e) [B,H,S,HD]; z==1: K [B,H,S,HD].
// z==2: V computed TRANSPOSED (A=W rows over D, B=X rows over tokens) so the
//       Vt [B,H,HD,S] store is 16-lane-contiguous 32B segments, not scatter.
// ---------------------------------------------------------------------------
__global__ __launch_bounds__(256) void qkv_gemm(
    const void* __restrict__ X0, const bf16* __restrict__ Xb,
    const void* __restrict__ W0, const void* __restrict__ W1, const void* __restrict__ W2,
    const void* __restrict__ b0, const void* __restrict__ b1, const void* __restrict__ b2,
    bf16* __restrict__ Qo, bf16* __restrict__ Ko, bf16* __restrict__ Vo,
    const bf16* __restrict__ Wb, const int* __restrict__ flagp) {
  const int z = blockIdx.z;
  const bool isf32 = *flagp != 0;
  const void* Worig = z == 0 ? W0 : z == 1 ? W1 : W2;
  const void* bias  = z == 0 ? b0 : z == 1 ? b1 : b2;
  bf16* out         = z == 0 ? Qo : z == 1 ? Ko : Vo;
  const bf16* Xs = isf32 ? Xb : (const bf16*)X0;
  const bf16* Ws = isf32 ? (Wb + (size_t)z * D * D) : (const bf16*)Worig;
  // z<2: A=X (rows=tokens, blockIdx.x), B=W (rows=d, blockIdx.y)
  // z=2: A=W (rows=d, blockIdx.y), B=X (rows=tokens, blockIdx.x)
  const bf16* Am = (z == 2) ? Ws : Xs;
  const bf16* Bm = (z == 2) ? Xs : Ws;
  const int bm = (z == 2 ? blockIdx.y : blockIdx.x) * 128;
  const int bn = (z == 2 ? blockIdx.x : blockIdx.y) * 128;

  __shared__ __align__(16) bf16 As[128 * 32];
  __shared__ __align__(16) bf16 Bs[128 * 32];
  const int tid = threadIdx.x, lane = tid & 63, wave = tid >> 6;
  const int q16 = lane & 15, quad = lane >> 4;
  const int wm = (wave & 1) * 64, wn = (wave >> 1) * 64;
  const int r0 = tid >> 2, kg = (tid & 3) * 8;

  f32x4 acc[4][4] = {};

  for (int k0 = 0; k0 < D; k0 += 32) {
    __syncthreads();
    gl_lds16(Am + (size_t)(bm + r0) * D + k0 + kg,      As + wave * 512 + lane * 8);
    gl_lds16(Am + (size_t)(bm + 64 + r0) * D + k0 + kg, As + (4 + wave) * 512 + lane * 8);
    gl_lds16(Bm + (size_t)(bn + r0) * D + k0 + kg,      Bs + wave * 512 + lane * 8);
    gl_lds16(Bm + (size_t)(bn + 64 + r0) * D + k0 + kg, Bs + (4 + wave) * 512 + lane * 8);
    __syncthreads();
    bf16x8 af[4], bfr[4];
#pragma unroll
    for (int i = 0; i < 4; i++) {
      af[i]  = *(const bf16x8*)(As + (wm + i * 16 + q16) * 32 + quad * 8);
      bfr[i] = *(const bf16x8*)(Bs + (wn + i * 16 + q16) * 32 + quad * 8);
    }
#pragma unroll
    for (int mi = 0; mi < 4; mi++)
#pragma unroll
      for (int ni = 0; ni < 4; ni++)
        acc[mi][ni] = MFMA(af[mi], bfr[ni], acc[mi][ni]);
  }

  const float scl = (z == 0) ? 0.125f * 1.44269504f : 1.0f;
#pragma unroll
  for (int mi = 0; mi < 4; mi++) {
#pragma unroll
    for (int ni = 0; ni < 4; ni++) {
      if (z == 2) {
        // rows = d-dim, cols = tokens; bias indexed by row
        const int gm0 = bm + wm + mi * 16 + quad * 4;   // d base
        const int gn  = bn + wn + ni * 16 + q16;        // token
        const int bt = gn >> 11, s = gn & 2047;
#pragma unroll
        for (int r = 0; r < 4; r++) {
          const int d = gm0 + r;
          const int h = d >> 6, hd = d & 63;
          out[((size_t)(bt * H + h) * HD + hd) * S + s] =
              (bf16)(acc[mi][ni][r] + load1(bias, d, isf32));
        }
      } else {
        const int gn = bn + wn + ni * 16 + q16;
        const float bb = load1(bias, gn, isf32);
        const int h = gn >> 6, hd = gn & 63;
        const int gm0 = bm + wm + mi * 16 + quad * 4;
        const int bidx = gm0 >> 11, s0 = gm0 & 2047;
#pragma unroll
        for (int r = 0; r < 4; r++)
          out[((size_t)(bidx * H + h) * S + (s0 + r)) * HD + hd] = (bf16)((acc[mi][ni][r] + bb) * scl);
      }
    }
  }
}

// ---------------------------------------------------------------------------
// Flash attention v5: zero LDS, zero barriers, 32 queries/wave (2 q-sets),
// 1024 blocks with XCD swizzle (same-head blocks share an XCD's L2).
// Permuted-K trick: Sc^T = K.Q^T with K rows loaded at
//   key(m) = 32*(ki>>1) + 8*quad + 4*(ki&1) + r   (m = 16*ki + 4*quad + r)
// so score regs are directly the B-frag of O^T = Vt.P^T in natural key order.
// No-max softmax; Q pre-scaled 0.125*log2e.
// Q,K: [BH,S,HD]; Vt: [BH,HD,S]; mask: [B,S]; out: [B,S,D]
// ---------------------------------------------------------------------------
__global__ __launch_bounds__(256, 4) void attn(
    const bf16* __restrict__ Q, const bf16* __restrict__ K,
    const bf16* __restrict__ Vt, const void* __restrict__ mask,
    void* __restrict__ outv, const int* __restrict__ flagp) {
  const bool isf32 = *flagp != 0;
  const int tid = threadIdx.x, lane = tid & 63, wave = tid >> 6;
  const int q16 = lane & 15, quad = lane >> 4;
  // swizzle: xcd = L&7 round-robin heuristic; same bh -> same XCD
  const int L = blockIdx.x;
  const int bh = (L & 7) * 8 + ((L >> 3) & 7);
  const int qc = L >> 6;                       // 0..15
  const int b = bh >> 4, h = bh & 15;
  const int qbase = qc * 128 + wave * 32;
  const float L2E = 1.44269504f;

  // Q B-frags for 2 q-sets
  bf16x8 qf[2][2];
#pragma unroll
  for (int qs = 0; qs < 2; qs++) {
    const bf16* qr = Q + ((size_t)bh * S + qbase + qs * 16 + q16) * HD;
    qf[qs][0] = *(const bf16x8*)(qr + quad * 8);
    qf[qs][1] = *(const bf16x8*)(qr + 32 + quad * 8);
  }

  f32x4 o[2][4] = {};   // [qs][hi]  O^T accum: row=hd_local, col=query
  float racc[2] = {};

  const bf16* Kb = K + (size_t)bh * S * HD;
  const bf16* Vb = Vt + (size_t)bh * HD * S;
  const int kprow = 8 * (q16 >> 2) + (q16 & 3);  // lane's permuted-key row part

  for (int t = 0; t < 32; t++) {
    const int kt = t * 64;
    bf16x8 kf[4][2];
#pragma unroll
    for (int ki = 0; ki < 4; ki++) {
      const bf16* kr = Kb + (size_t)(kt + 32 * (ki >> 1) + 4 * (ki & 1) + kprow) * HD;
      kf[ki][0] = *(const bf16x8*)(kr + quad * 8);
      kf[ki][1] = *(const bf16x8*)(kr + 32 + quad * 8);
    }
    f32x4 mk[4];
#pragma unroll
    for (int ki = 0; ki < 4; ki++) {
      f32x4 mv = load4(mask, (size_t)b * S + kt + 32 * (ki >> 1) + 4 * (ki & 1) + 8 * quad, isf32);
#pragma unroll
      for (int r = 0; r < 4; r++) mk[ki][r] = mv[r] * L2E;
    }

    bf16x8 pb[2][2];
#pragma unroll
    for (int qs = 0; qs < 2; qs++) {
      f32x4 sc[4];
#pragma unroll
      for (int ki = 0; ki < 4; ki++) {
        f32x4 zz = {0.f, 0.f, 0.f, 0.f};
        zz = MFMA(kf[ki][0], qf[qs][0], zz);
        sc[ki] = MFMA(kf[ki][1], qf[qs][1], zz);
      }
#pragma unroll
      for (int ki = 0; ki < 4; ki++) {
        const int hh = ki >> 1, half = (ki & 1) * 4;
#pragma unroll
        for (int r = 0; r < 4; r++) {
          const float p = __builtin_amdgcn_exp2f(sc[ki][r] + mk[ki][r]);
          racc[qs] += p;
          pb[qs][hh][half + r] = (bf16)p;
        }
      }
    }
    // O^T += Vt . P^T  (V frags loaded per hi, reused for both q-sets)
#pragma unroll
    for (int hi = 0; hi < 4; hi++) {
      const bf16* vr = Vb + (size_t)(hi * 16 + q16) * S + kt;
      const bf16x8 vf0 = *(const bf16x8*)(vr + quad * 8);
      const bf16x8 vf1 = *(const bf16x8*)(vr + 32 + quad * 8);
#pragma unroll
      for (int qs = 0; qs < 2; qs++) {
        o[qs][hi] = MFMA(vf0, pb[qs][0], o[qs][hi]);
        o[qs][hi] = MFMA(vf1, pb[qs][1], o[qs][hi]);
      }
    }
  }

  // rowsum: reduce across the 4 quads holding the same query q16
#pragma unroll
  for (int qs = 0; qs < 2; qs++) {
    racc[qs] += __shfl_xor(racc[qs], 16);
    racc[qs] += __shfl_xor(racc[qs], 32);
  }

  // epilogue: out[b, qbase+qs*16+q16, h*64 + hi*16 + quad*4 + r] = o/racc
#pragma unroll
  for (int qs = 0; qs < 2; qs++) {
    const float inv = 1.0f / racc[qs];
    const size_t row = (size_t)b * S + qbase + qs * 16 + q16;
#pragma unroll
    for (int hi = 0; hi < 4; hi++) {
      const size_t off = row * D + h * HD + hi * 16 + quad * 4;
      if (isf32) {
        float4 st;
        st.x = o[qs][hi][0] * inv; st.y = o[qs][hi][1] * inv;
        st.z = o[qs][hi][2] * inv; st.w = o[qs][hi][3] * inv;
        *(float4*)((float*)outv + off) = st;
      } else {
        bf16x4 st;
#pragma unroll
        for (int r = 0; r < 4; r++) st[r] = (bf16)(o[qs][hi][r] * inv);
        *(bf16x4*)((bf16*)outv + off) = st;
      }
    }
  }
}

// ---------------------------------------------------------------------------
extern "C" void kernel_launch(void* const* d_in, const int* in_sizes, int n_in,
                              void* d_out, int out_size, void* d_ws, size_t ws_size,
                              hipStream_t stream) {
  const void* X    = d_in[0];
  const void* mask = d_in[1];
  const void* Wq = d_in[2]; const void* bq = d_in[3];
  const void* Wk = d_in[4]; const void* bk = d_in[5];
  const void* Wv = d_in[6]; const void* bv = d_in[7];

  const size_t elems = (size_t)M * D;  // 8 Mi
  bf16* Qw = (bf16*)d_ws;
  bf16* Kw = Qw + elems;
  bf16* Vw = Kw + elems;
  int* flag = (int*)(Vw + elems);

  // fp32 case: d_out (32 MB) stages bf16 X (16MB) + W (6MB).
  bf16* Xb = (bf16*)d_out;
  bf16* Wb = Xb + elems;

  detect_dtype<<<1, 256, 0, stream>>>((const uint4*)X, flag);
  convert_inputs<<<dim3(4096, 4), 256, 0, stream>>>(X, Wq, Wk, Wv, Xb, Wb, flag);
  qkv_gemm<<<dim3(M / 128, D / 128, 3), 256, 0, stream>>>(
      X, Xb, Wq, Wk, Wv, bq, bk, bv, Qw, Kw, Vw, Wb, flag);
  attn<<<dim3(1024), 256, 0, stream>>>(Qw, Kw, Vw, mask, d_out, flag);
}